// Round 8
// baseline (560.025 us; speedup 1.0000x reference)
//
#include <hip/hip_runtime.h>
#include <hip/hip_bf16.h>

#define NT 4           // node types (labels)
#define FEAT 256       // nfeat == nhid
#define OUT3 64        // nclass
#define CAP 10240      // fixed bucket capacity (mean 8192, +22 sigma)

typedef __bf16 bf16x8 __attribute__((ext_vector_type(8)));
typedef float  f32x4  __attribute__((ext_vector_type(4)));
typedef unsigned long long u64;

__device__ inline unsigned int f2bf_bits(float f) {
    __hip_bfloat16 h = __float2bfloat16(f);   // RNE
    unsigned short u;
    __builtin_memcpy(&u, &h, 2);
    return (unsigned int)u;
}
__device__ inline float bfl(unsigned int u) { return __uint_as_float(u << 16); }
__device__ inline float bfh(unsigned int u) { return __uint_as_float(u & 0xffff0000u); }
// stored feature pos p (pi order) -> natural feature index, within each 64-block
__device__ __host__ inline int nat_of(int p) {
    int lo = p & 63;
    return (p & ~63) | (((lo & 3) << 4) | (lo >> 2));
}
// non-temporal helpers
__device__ inline u64 ntl64(const void* p) { return __builtin_nontemporal_load((const u64*)p); }
__device__ inline int ntl32i(const void* p) { return __builtin_nontemporal_load((const int*)p); }
__device__ inline float ntlf(const void* p) { return __builtin_nontemporal_load((const float*)p); }
__device__ inline void nts64(void* p, u64 v) { __builtin_nontemporal_store(v, (u64*)p); }
__device__ inline void nts32(void* p, unsigned int v) { __builtin_nontemporal_store(v, (unsigned int*)p); }
__device__ inline void ntsf(void* p, float v) { __builtin_nontemporal_store(v, (float*)p); }
__device__ inline void nts16(void* p, unsigned short v) { __builtin_nontemporal_store(v, (unsigned short*)p); }

// ---------------- label histogram ----------------
__global__ __launch_bounds__(512) void label_hist(const int* __restrict__ labels,
                                                  int* __restrict__ lc, int N) {
    __shared__ int lh[NT];
    int tid = threadIdx.x;
    if (tid < NT) lh[tid] = 0;
    __syncthreads();
    int base = blockIdx.x * 4096;
#pragma unroll
    for (int k = 0; k < 8; ++k) {
        int i = base + k * 512 + tid;
        if (i < N) atomicAdd(&lh[labels[i]], 1);
    }
    __syncthreads();
    if (tid < NT) { int v = lh[tid]; if (v) atomicAdd(&lc[tid], v); }
}

// ------- node scatter: build iperm (orig -> label-sorted slot); lstart inline from lc -----
__global__ void scatter_nodes(const int* __restrict__ labels, const int* __restrict__ lc,
                              int* __restrict__ lcur, int* __restrict__ iperm, int N) {
    int lst[NT];
    {
        int run = 0;
#pragma unroll
        for (int l = 0; l < NT; ++l) { lst[l] = run; run += (lc[l] + 63) & ~63; }
    }
    int n = blockIdx.x * 256 + threadIdx.x;
    int lab = (n < N) ? labels[n] : -1;
    int lane = threadIdx.x & 63;
    for (int l = 0; l < NT; ++l) {
        unsigned long long m = __ballot(lab == l);
        if (m == 0ull) continue;
        int leader = __builtin_ctzll(m);
        int base = 0;
        if (lane == leader) base = atomicAdd(&lcur[l], (int)__popcll(m));
        base = __shfl(base, leader, 64);
        if (lab == l) {
            int prefix = (int)__popcll(m & ((1ull << lane) - 1ull));
            iperm[n] = lst[l] + base + prefix;
        }
    }
}

// ================= FUSE_A: scatter_edges + cast_x + cast_w_all =================
// seg 0 [0, nbEB): edge scatter into fixed-cap bucket regions (bucket = dst>>8)
//   earr rec (u64): low32 = slot | (dst&255)<<16 ; high32 = w fp32 bits
// seg 1 [nbEB, nbEB+nbX): cast x -> bf16 half-split slot rows
// seg 2 rest: cast W1/W2/W3 -> swizzled bf16 + permuted biases
__global__ __launch_bounds__(512) void fuse_a(
    const int* __restrict__ src, const int* __restrict__ dst, const float* __restrict__ w,
    const int* __restrict__ iperm, int* __restrict__ gcur, u64* __restrict__ earr, int E,
    const float* __restrict__ x, unsigned short* __restrict__ actLo,
    unsigned short* __restrict__ actHi, int total4,
    const float* __restrict__ W1, const float* __restrict__ W2, const float* __restrict__ W3,
    const float* __restrict__ b1, const float* __restrict__ b2,
    unsigned short* __restrict__ W1b, unsigned short* __restrict__ W2b,
    unsigned short* __restrict__ W3b, float* __restrict__ biasPerm,
    int nbEB, int nbX) {
    int tid = threadIdx.x;
    int blk = (int)blockIdx.x;
    if (blk < nbEB) {
        // ---- edge scatter ----
        __shared__ int h[256];
        __shared__ int basearr[256];
        if (tid < 256) h[tid] = 0;
        __syncthreads();
        int base = blk * 4096;
        int b[8], rank[8], px[8]; float wv[8];
#pragma unroll
        for (int k = 0; k < 8; ++k) {
            int e = base + k * 512 + tid;
            if (e < E) {
                int d = ntl32i(dst + e);
                b[k] = ((unsigned)d) >> 8;
                px[k] = iperm[ntl32i(src + e)] | ((d & 255) << 16);
                wv[k] = ntlf(w + e);
                rank[k] = atomicAdd(&h[b[k]], 1);
            } else b[k] = -1;
        }
        __syncthreads();
        if (tid < 256) { int c = h[tid]; basearr[tid] = c ? atomicAdd(&gcur[tid], c) : 0; }
        __syncthreads();
#pragma unroll
        for (int k = 0; k < 8; ++k) {
            if (b[k] >= 0) {
                size_t pos = (size_t)b[k] * CAP + basearr[b[k]] + rank[k];
                nts64(&earr[pos], (u64)(unsigned)px[k] | ((u64)__float_as_uint(wv[k]) << 32));
            }
        }
    } else if (blk < nbEB + nbX) {
        // ---- cast x (fp32 -> bf16, half-split, slot-scattered) ----
        int i = (blk - nbEB) * 512 + tid;
        if (i < total4) {
            const u64* xp = (const u64*)x + (size_t)i * 2;
            u64 w0 = ntl64(xp), w1 = ntl64(xp + 1);
            float f0 = __uint_as_float((unsigned)w0), f1 = __uint_as_float((unsigned)(w0 >> 32));
            float f2 = __uint_as_float((unsigned)w1), f3 = __uint_as_float((unsigned)(w1 >> 32));
            unsigned int lo = f2bf_bits(f0) | (f2bf_bits(f1) << 16);
            unsigned int hi = f2bf_bits(f2) | (f2bf_bits(f3) << 16);
            int slot = iperm[i >> 6];
            u64* dp = (u64*)(((i & 63) >= 32) ? actHi : actLo);
            nts64(dp + (size_t)slot * 32 + (i & 31), (u64)lo | ((u64)hi << 32));
        }
    } else {
        // ---- cast W + biases ----
        const int S = NT * FEAT * FEAT;
        const int S3 = NT * FEAT * OUT3;
        int idx = (blk - nbEB - nbX) * 512 + tid;
        if (idx < 2 * S + S3) {
            const float* W; unsigned short* D; int OUTF; int t; bool remap;
            if (idx < S)          { W = W1; D = W1b; OUTF = FEAT; t = idx;         remap = false; }
            else if (idx < 2 * S) { W = W2; D = W2b; OUTF = FEAT; t = idx - S;     remap = true; }
            else                  { W = W3; D = W3b; OUTF = OUT3; t = idx - 2 * S; remap = true; }
            int n = t % OUTF;
            int r = t / OUTF;              // lab*256 + k_slot
            int j = r & 7, q = (r >> 3) & 3, k0 = (r >> 5) & 7, lab = r >> 8;
            int k_slot = k0 * 32 + q * 8 + j;
            int k_src = remap ? nat_of(k_slot) : k_slot;
            float f = ntlf(&W[((size_t)(lab * FEAT + k_src)) * OUTF + n]);
            nts16(&D[(((size_t)lab * 8 + k0) * OUTF + n) * 32 + q * 8 + j],
                  (unsigned short)f2bf_bits(f));
        } else {
            int p2 = idx - (2 * S + S3);
            if (p2 < 256) biasPerm[p2] = b1[nat_of(p2)];
            else if (p2 < 512) biasPerm[p2] = b2[nat_of(p2 - 256)];
        }
    }
}

// ------- bucket sort body: within-bucket counting sort -> rs/re + 4B edge records -------
// final record: (w_bf16 << 16) | src_slot
__device__ void bucket_sort_body(int b, const u64* __restrict__ earr,
                                 const int* __restrict__ gcur,
                                 int* __restrict__ rs, int* __restrict__ re,
                                 unsigned int* __restrict__ edata, int N) {
    int s = b * CAP;
    int cnt = gcur[b];
    int e = s + cnt;
    __shared__ int cntS[256], off[256];
    int tid = threadIdx.x;
    cntS[tid] = 0;
    __syncthreads();
    for (int i = s + tid; i < e; i += 256) {
        u64 r = ntl64(&earr[i]);
        atomicAdd(&cntS[((unsigned)r >> 16) & 255], 1);
    }
    __syncthreads();
    off[tid] = cntS[tid];
    __syncthreads();
    for (int d = 1; d < 256; d <<= 1) {
        int v = (tid >= d) ? off[tid - d] : 0;
        __syncthreads();
        off[tid] += v;
        __syncthreads();
    }
    int excl = off[tid] - cntS[tid];
    int node = b * 256 + tid;
    if (node < N) { rs[node] = s + excl; re[node] = s + excl + cntS[tid]; }
    off[tid] = excl;
    __syncthreads();
    for (int i = s + tid; i < e; i += 256) {
        u64 r = ntl64(&earr[i]);
        unsigned int lo32 = (unsigned int)r;
        int d2 = (lo32 >> 16) & 255;
        int k = atomicAdd(&off[d2], 1);
        nts32(&edata[s + k],
              (f2bf_bits(__uint_as_float((unsigned)(r >> 32))) << 16) | (lo32 & 0xffff));
    }
}

// ------- proj 256-out body: dense 64 slots x 256 outs per block, half-split I/O -------
__device__ void proj256_body(int gb,
                             const unsigned short* __restrict__ actLo,
                             const unsigned short* __restrict__ actHi,
                             const unsigned short* __restrict__ Wswz,
                             const int* __restrict__ lc,
                             unsigned short* __restrict__ supLo,
                             unsigned short* __restrict__ supHi) {
    int warp = threadIdx.x >> 6;
    int lane = threadIdx.x & 63;
    int m0 = gb * 64;
    int c0 = (lc[0] + 63) & ~63, c1 = (lc[1] + 63) & ~63, c2 = (lc[2] + 63) & ~63;
    int lab = (m0 >= c0) + (m0 >= c0 + c1) + (m0 >= c0 + c1 + c2);
    int q = lane >> 4, c = lane & 15;
    int n0 = warp * 64;

    const unsigned short* aLo = actLo + (size_t)(m0 + c) * 128 + q * 8;
    const unsigned short* aHi = actHi + (size_t)(m0 + c) * 128 + q * 8;
    const unsigned short* bb = Wswz + (size_t)lab * FEAT * 256 + (size_t)(n0 + c) * 32 + q * 8;

    f32x4 acc[4][4] = {};
#pragma unroll
    for (int k0 = 0; k0 < 8; ++k0) {
        const unsigned short* abase = (k0 < 4) ? aLo : aHi;
        int koff = (k0 & 3) * 32;
        bf16x8 a[4];
#pragma unroll
        for (int t = 0; t < 4; ++t) a[t] = *(const bf16x8*)(abase + (size_t)t * 2048 + koff);
        const unsigned short* bk = bb + (size_t)k0 * 32 * 256;
#pragma unroll
        for (int u = 0; u < 4; ++u) {
            bf16x8 bfrag = *(const bf16x8*)(bk + u * 512);
#pragma unroll
            for (int t = 0; t < 4; ++t)
                acc[t][u] = __builtin_amdgcn_mfma_f32_16x16x32_bf16(a[t], bfrag, acc[t][u], 0, 0, 0);
        }
    }
    // pi-store: row = m0+t*16+q*4+r ; lane writes p = n0 + c*4 + u -> half n0>>7
    u64* ov = (u64*)((n0 >= 128) ? supHi : supLo);
    int cix = ((n0 & 64) >> 2) + c;
#pragma unroll
    for (int t = 0; t < 4; ++t) {
#pragma unroll
        for (int r = 0; r < 4; ++r) {
            int row = m0 + t * 16 + q * 4 + r;
            unsigned int lo = f2bf_bits(acc[t][0][r]) | (f2bf_bits(acc[t][1][r]) << 16);
            unsigned int hi = f2bf_bits(acc[t][2][r]) | (f2bf_bits(acc[t][3][r]) << 16);
            nts64(&ov[(size_t)row * 32 + cix], (u64)lo | ((u64)hi << 32));
        }
    }
}

// ================= FUSE_B: bucket_sort (blocks [0,NB)) + proj256 L1 (rest) =================
__global__ __launch_bounds__(256) void fuse_b(
    const u64* __restrict__ earr, const int* __restrict__ gcur,
    int* __restrict__ rs, int* __restrict__ re, unsigned int* __restrict__ edata,
    int N, int NB,
    const unsigned short* __restrict__ actLo, const unsigned short* __restrict__ actHi,
    const unsigned short* __restrict__ Wswz, const int* __restrict__ lc,
    unsigned short* __restrict__ supLo, unsigned short* __restrict__ supHi) {
    int blk = (int)blockIdx.x;
    if (blk < NB) bucket_sort_body(blk, earr, gcur, rs, re, edata, N);
    else proj256_body(blk - NB, actLo, actHi, Wswz, lc, supLo, supHi);
}

// ---------------- standalone proj 256 (layer 2) ----------------
__global__ __launch_bounds__(256) void proj256_kernel(
    const unsigned short* __restrict__ actLo, const unsigned short* __restrict__ actHi,
    const unsigned short* __restrict__ Wswz, const int* __restrict__ lc,
    unsigned short* __restrict__ supLo, unsigned short* __restrict__ supHi) {
    proj256_body((int)blockIdx.x, actLo, actHi, Wswz, lc, supLo, supHi);
}

// ---------------- proj 64-out: dense 64 slots x 64 outs per block, half-split input ------
__global__ __launch_bounds__(256) void proj64_kernel(
    const unsigned short* __restrict__ actLo, const unsigned short* __restrict__ actHi,
    const unsigned short* __restrict__ Wswz, const int* __restrict__ lc,
    unsigned short* __restrict__ outp) {
    int warp = threadIdx.x >> 6;
    int lane = threadIdx.x & 63;
    int m0 = blockIdx.x * 64;
    int c0 = (lc[0] + 63) & ~63, c1 = (lc[1] + 63) & ~63, c2 = (lc[2] + 63) & ~63;
    int lab = (m0 >= c0) + (m0 >= c0 + c1) + (m0 >= c0 + c1 + c2);
    int q = lane >> 4, c = lane & 15;
    int mb = m0 + warp * 16;

    const unsigned short* aLo = actLo + (size_t)(mb + c) * 128 + q * 8;
    const unsigned short* aHi = actHi + (size_t)(mb + c) * 128 + q * 8;
    const unsigned short* bb = Wswz + (size_t)lab * FEAT * OUT3 + (size_t)c * 32 + q * 8;

    f32x4 acc[4] = {};
#pragma unroll
    for (int k0 = 0; k0 < 8; ++k0) {
        const unsigned short* abase = (k0 < 4) ? aLo : aHi;
        bf16x8 a = *(const bf16x8*)(abase + (k0 & 3) * 32);
        const unsigned short* bk = bb + (size_t)k0 * 32 * OUT3;
#pragma unroll
        for (int u = 0; u < 4; ++u) {
            bf16x8 bfrag = *(const bf16x8*)(bk + u * 512);
            acc[u] = __builtin_amdgcn_mfma_f32_16x16x32_bf16(a, bfrag, acc[u], 0, 0, 0);
        }
    }
    u64* ov = (u64*)outp;
#pragma unroll
    for (int r = 0; r < 4; ++r) {
        int row = mb + q * 4 + r;
        unsigned int lo = f2bf_bits(acc[0][r]) | (f2bf_bits(acc[1][r]) << 16);
        unsigned int hi = f2bf_bits(acc[2][r]) | (f2bf_bits(acc[3][r]) << 16);
        nts64(&ov[(size_t)row * 16 + c], (u64)lo | ((u64)hi << 32));
    }
}

// ------- aggregation over ONE feature half (128 feats): one wave per node, unroll 16 -----
// sup half row = 64 uints (256B). lane handles stored pos p = half*128 + 2*lane, +1.
__global__ __launch_bounds__(256) void agg256h_kernel(
    const unsigned int* __restrict__ sup, const int* __restrict__ rs,
    const int* __restrict__ re, const unsigned int* __restrict__ edata,
    const int* __restrict__ iperm, const float* __restrict__ biasHalf,
    unsigned int* __restrict__ outp, int N) {
    int warp = __builtin_amdgcn_readfirstlane((int)(threadIdx.x >> 6));
    int node = (int)blockIdx.x * 4 + warp;
    if (node >= N) return;
    int lane = threadIdx.x & 63;
    int s = __builtin_amdgcn_readfirstlane(rs[node]);
    int e = __builtin_amdgcn_readfirstlane(re[node]);
    int slot = __builtin_amdgcn_readfirstlane(iperm[node]);
    float a0 = 0.f, a1 = 0.f;
    int j = s;
    for (; j + 16 <= e; j += 16) {
        unsigned int ed[16], v[16];
#pragma unroll
        for (int u = 0; u < 16; ++u) ed[u] = edata[j + u];
#pragma unroll
        for (int u = 0; u < 16; ++u) v[u] = sup[(size_t)(ed[u] & 0xffff) * 64 + lane];
#pragma unroll
        for (int u = 0; u < 16; ++u) {
            float w = __uint_as_float(ed[u] & 0xffff0000u);
            a0 += w * bfl(v[u]); a1 += w * bfh(v[u]);
        }
    }
    if (j < e) {   // masked tail (<=15 real edges)
        unsigned int ed[16], v[16]; float wm[16];
#pragma unroll
        for (int u = 0; u < 16; ++u) {
            int jj = j + u;
            int jc = (jj < e) ? jj : e - 1;
            ed[u] = edata[jc];
            wm[u] = (jj < e) ? __uint_as_float(ed[u] & 0xffff0000u) : 0.f;
        }
#pragma unroll
        for (int u = 0; u < 16; ++u) v[u] = sup[(size_t)(ed[u] & 0xffff) * 64 + lane];
#pragma unroll
        for (int u = 0; u < 16; ++u) { a0 += wm[u] * bfl(v[u]); a1 += wm[u] * bfh(v[u]); }
    }
    float2 b = ((const float2*)biasHalf)[lane];
    a0 = fmaxf(a0 + b.x, 0.f);
    a1 = fmaxf(a1 + b.y, 0.f);
    nts32(&outp[(size_t)slot * 64 + lane], f2bf_bits(a0) | (f2bf_bits(a1) << 16));
}

// ---------------- aggregation, 64-feat: one wave per node (lane = stored pos), fp32 out --
__global__ __launch_bounds__(256) void agg64_kernel(
    const unsigned short* __restrict__ sup, const int* __restrict__ rs,
    const int* __restrict__ re, const unsigned int* __restrict__ edata,
    const float* __restrict__ b3, float* __restrict__ outp, int N) {
    int warp = __builtin_amdgcn_readfirstlane((int)(threadIdx.x >> 6));
    int node = (int)blockIdx.x * 4 + warp;
    if (node >= N) return;
    int lane = threadIdx.x & 63;
    int s = __builtin_amdgcn_readfirstlane(rs[node]);
    int e = __builtin_amdgcn_readfirstlane(re[node]);
    float a = 0.f;
    int j = s;
    for (; j + 8 <= e; j += 8) {
        unsigned int ed[8]; unsigned short v[8];
#pragma unroll
        for (int u = 0; u < 8; ++u) ed[u] = edata[j + u];
#pragma unroll
        for (int u = 0; u < 8; ++u) v[u] = sup[(size_t)(ed[u] & 0xffff) * 64 + lane];
#pragma unroll
        for (int u = 0; u < 8; ++u)
            a += __uint_as_float(ed[u] & 0xffff0000u) * __uint_as_float((unsigned int)v[u] << 16);
    }
    if (j < e) {
        unsigned int ed[8]; float wm[8]; unsigned short v[8];
#pragma unroll
        for (int u = 0; u < 8; ++u) {
            int jj = j + u;
            int jc = (jj < e) ? jj : e - 1;
            ed[u] = edata[jc];
            wm[u] = (jj < e) ? __uint_as_float(ed[u] & 0xffff0000u) : 0.f;
        }
#pragma unroll
        for (int u = 0; u < 8; ++u) v[u] = sup[(size_t)(ed[u] & 0xffff) * 64 + lane];
#pragma unroll
        for (int u = 0; u < 8; ++u)
            a += wm[u] * __uint_as_float((unsigned int)v[u] << 16);
    }
    int natp = (((lane & 3) << 4) | (lane >> 2));    // un-permute pi within the 64 outs
    ntsf(&outp[(size_t)node * 64 + natp], a + b3[natp]);
}

extern "C" void kernel_launch(void* const* d_in, const int* in_sizes, int n_in,
                              void* d_out, int out_size, void* d_ws, size_t ws_size,
                              hipStream_t stream) {
    const float* x        = (const float*)d_in[0];
    const int*   edge_src = (const int*)d_in[1];
    const int*   edge_dst = (const int*)d_in[2];
    const float* edge_w   = (const float*)d_in[3];
    const int*   labels   = (const int*)d_in[4];
    const float* W1 = (const float*)d_in[5];
    const float* b1 = (const float*)d_in[6];
    const float* W2 = (const float*)d_in[7];
    const float* b2 = (const float*)d_in[8];
    const float* W3 = (const float*)d_in[9];
    const float* b3 = (const float*)d_in[10];

    const int N = in_sizes[0] / FEAT;
    const int E = in_sizes[1];
    const int NB = (N + 255) >> 8;                    // dst buckets (orig id space)
    const int G64 = (N + NT * 64 + 63) / 64;          // slot-space 64-row tiles (upper bound)
    const int slotCap = G64 * 64;

    // ---- workspace carve (256B aligned) ----
    char* p = (char*)d_ws;
    auto alloc = [&](size_t bytes) -> char* {
        char* r = p;
        p += (bytes + 255) & ~(size_t)255;
        return r;
    };
    unsigned short* bufA = (unsigned short*)alloc((size_t)slotCap * FEAT * 2);
    unsigned short* bufB = (unsigned short*)alloc((size_t)slotCap * FEAT * 2);
    unsigned short* W1b  = (unsigned short*)alloc((size_t)NT * FEAT * FEAT * 2);
    unsigned short* W2b  = (unsigned short*)alloc((size_t)NT * FEAT * FEAT * 2);
    unsigned short* W3b  = (unsigned short*)alloc((size_t)NT * FEAT * OUT3 * 2);
    float*        biasPerm = (float*)alloc(512 * 4);
    int*          rs     = (int*)alloc((size_t)N * 4);
    int*          re     = (int*)alloc((size_t)N * 4);
    unsigned int* edata  = (unsigned int*)alloc((size_t)NB * CAP * 4);
    u64*          earr   = (u64*)alloc((size_t)NB * CAP * 8);
    int*          iperm  = (int*)alloc((size_t)N * 4);
    int*          counters = (int*)alloc(264 * 4);    // gcur[256] + lc[4] + lcur[4]
    int* gcur = counters;
    int* lc   = counters + 256;
    int* lcur = counters + 260;

    // half-table views (lo = feats p<128, hi = p>=128), each slotCap*128 ushorts
    unsigned short* actLo = bufA;
    unsigned short* actHi = bufA + (size_t)slotCap * 128;
    unsigned short* supLo = bufB;
    unsigned short* supHi = bufB + (size_t)slotCap * 128;

    const int nbEB = (E + 4095) / 4096;
    const int total4 = N * 64;                        // float4 groups in x
    const int nbX = (total4 + 511) / 512;
    const int totW = 2 * NT * FEAT * FEAT + NT * FEAT * OUT3 + 512;
    const int nbW = (totW + 511) / 512;

    // ---- CSR build + label-sort + casts ----
    hipMemsetAsync(counters, 0, 264 * 4, stream);
    label_hist<<<(N + 4095) / 4096, 512, 0, stream>>>(labels, lc, N);
    scatter_nodes<<<(N + 255) / 256, 256, 0, stream>>>(labels, lc, lcur, iperm, N);
    fuse_a<<<nbEB + nbX + nbW, 512, 0, stream>>>(
        edge_src, edge_dst, edge_w, iperm, gcur, earr, E,
        x, actLo, actHi, total4,
        W1, W2, W3, b1, b2, W1b, W2b, W3b, biasPerm, nbEB, nbX);

    const int aggGrid = (N + 3) / 4;
    // ---- layer 1 (bucket_sort overlapped with proj256-L1) ----
    fuse_b<<<NB + G64, 256, 0, stream>>>(earr, gcur, rs, re, edata, N, NB,
                                         actLo, actHi, W1b, lc, supLo, supHi);
    agg256h_kernel<<<aggGrid, 256, 0, stream>>>((const unsigned int*)supLo, rs, re, edata, iperm,
                                                biasPerm + 0, (unsigned int*)actLo, N);
    agg256h_kernel<<<aggGrid, 256, 0, stream>>>((const unsigned int*)supHi, rs, re, edata, iperm,
                                                biasPerm + 128, (unsigned int*)actHi, N);
    // ---- layer 2 ----
    proj256_kernel<<<G64, 256, 0, stream>>>(actLo, actHi, W2b, lc, supLo, supHi);
    agg256h_kernel<<<aggGrid, 256, 0, stream>>>((const unsigned int*)supLo, rs, re, edata, iperm,
                                                biasPerm + 256, (unsigned int*)actLo, N);
    agg256h_kernel<<<aggGrid, 256, 0, stream>>>((const unsigned int*)supHi, rs, re, edata, iperm,
                                                biasPerm + 384, (unsigned int*)actHi, N);
    // ---- layer 3 ----
    proj64_kernel<<<G64, 256, 0, stream>>>(actLo, actHi, W3b, lc, bufB);
    agg64_kernel<<<aggGrid, 256, 0, stream>>>(bufB, rs, re, edata, b3, (float*)d_out, N);
}